// Round 5
// baseline (270.545 us; speedup 1.0000x reference)
//
#include <hip/hip_runtime.h>
#include <hip/hip_bf16.h>

#define NROWS 16384      // total feats rows
#define NHALF 8192       // normal rows
#define KDIM  256
#define TMARGIN 100.0f

typedef __bf16 bf16x8 __attribute__((ext_vector_type(8)));
typedef __bf16 bf16x4 __attribute__((ext_vector_type(4)));
typedef float  f32x4  __attribute__((ext_vector_type(4)));

// Static device scratch (avoids depending on ws_size); fully rewritten every call.
__device__ __bf16 g_bf[NROWS * KDIM];        // bf16 copy of feats
__device__ float  g_sq[NROWS];               // row squared norms (fp32)
__device__ float  g_part[4 * NROWS];         // per-column partial max/min of (sqa - 2c)

// ---------------- Kernel 1: convert fp32 -> bf16, compute row norms ----------------
__global__ __launch_bounds__(256) void prep_kernel(const float* __restrict__ feats) {
    int w    = threadIdx.x >> 6;
    int lane = threadIdx.x & 63;
    int row  = blockIdx.x * 4 + w;          // grid = NROWS/4 blocks

    const float* rp = feats + (size_t)row * KDIM + lane * 4;
    float4 v = *(const float4*)rp;

    bf16x4 b;
    b[0] = (__bf16)v.x; b[1] = (__bf16)v.y; b[2] = (__bf16)v.z; b[3] = (__bf16)v.w;
    *(bf16x4*)(g_bf + (size_t)row * KDIM + lane * 4) = b;

    float sq = v.x*v.x + v.y*v.y + v.z*v.z + v.w*v.w;
    #pragma unroll
    for (int off = 32; off > 0; off >>= 1) sq += __shfl_xor(sq, off);
    if (lane == 0) g_sq[row] = sq;
}

// ---------------- Kernel 2: fused distance GEMM + column max/min fold ----------------
// Block: 256 thr = 4 waves (2 row-halves x 2 col-halves). Block tile: 128 rows/iter x 128 cols.
// Wave tile: 64x64 via 4x4 grid of 16x16x32 bf16 MFMA, K=256 fully unrolled (8 k-steps).
// B fragments (this block's 128 columns x K) live in registers for the whole kernel.
__global__ __launch_bounds__(256, 1) void dist_kernel() {
    int tid  = threadIdx.x;
    int w    = tid >> 6;
    int lane = tid & 63;
    int wr   = w >> 1;             // row half (0/1)
    int wc   = w & 1;              // col half (0/1)
    int l15  = lane & 15;
    int lh   = lane >> 4;          // 0..3

    int colblock = blockIdx.x;                 // 0..127
    int ms       = blockIdx.y;                 // 0..1 (M split)
    int colbase  = colblock * 128 + wc * 64;
    bool minmode = (colblock * 128) >= NHALF;  // uniform per block

    // ---- load B fragments once: 4 col-tiles x 8 k-steps (128 VGPRs) ----
    bf16x8 Bfrag[4][8];
    #pragma unroll
    for (int n = 0; n < 4; ++n) {
        int col = colbase + n * 16 + l15;
        const __bf16* bp = g_bf + (size_t)col * KDIM + lh * 8;
        #pragma unroll
        for (int s = 0; s < 8; ++s)
            Bfrag[n][s] = *(const bf16x8*)(bp + s * 32);
    }

    float init = minmode ? 3.0e38f : -3.0e38f;
    float m_run[4] = {init, init, init, init};

    int row_lo = ms * 4096 + wr * 64;

    for (int it = 0; it < 32; ++it) {
        int rbase = row_lo + it * 128;

        f32x4 acc[4][4];
        #pragma unroll
        for (int m = 0; m < 4; ++m)
            #pragma unroll
            for (int n = 0; n < 4; ++n)
                acc[m][n] = (f32x4){0.f, 0.f, 0.f, 0.f};

        #pragma unroll
        for (int s = 0; s < 8; ++s) {
            bf16x8 a[4];
            #pragma unroll
            for (int m = 0; m < 4; ++m) {
                int row = rbase + m * 16 + l15;
                a[m] = *(const bf16x8*)(g_bf + (size_t)row * KDIM + s * 32 + lh * 8);
            }
            #pragma unroll
            for (int m = 0; m < 4; ++m)
                #pragma unroll
                for (int n = 0; n < 4; ++n)
                    acc[m][n] = __builtin_amdgcn_mfma_f32_16x16x32_bf16(
                        a[m], Bfrag[n][s], acc[m][n], 0, 0, 0);
        }

        // epilogue: fold t = sqa[row] - 2*c into per-column running max/min
        #pragma unroll
        for (int m = 0; m < 4; ++m) {
            f32x4 sq = *(const f32x4*)(g_sq + rbase + m * 16 + lh * 4);
            #pragma unroll
            for (int n = 0; n < 4; ++n) {
                #pragma unroll
                for (int r = 0; r < 4; ++r) {
                    float t = sq[r] - 2.0f * acc[m][n][r];
                    m_run[n] = minmode ? fminf(m_run[n], t) : fmaxf(m_run[n], t);
                }
            }
        }
    }

    // lanes {l, l^16, l^32, l^48} hold the same column (different row sub-groups)
    #pragma unroll
    for (int n = 0; n < 4; ++n) {
        float v = m_run[n];
        float v1 = __shfl_xor(v, 16);
        v = minmode ? fminf(v, v1) : fmaxf(v, v1);
        v1 = __shfl_xor(v, 32);
        v = minmode ? fminf(v, v1) : fmaxf(v, v1);
        m_run[n] = v;
    }
    if (lane < 16) {
        int pslot = ms * 2 + wr;
        #pragma unroll
        for (int n = 0; n < 4; ++n)
            g_part[pslot * NROWS + colbase + n * 16 + lane] = m_run[n];
    }
}

// ---------------- Kernel 3: combine partials, sqrt, means, scalar out ----------------
__global__ __launch_bounds__(256) void finish_kernel(float* __restrict__ out) {
    int tid = threadIdx.x;
    float s1 = 0.f, s2 = 0.f;
    for (int j = tid; j < NROWS; j += 256) {
        float p0 = g_part[0 * NROWS + j];
        float p1 = g_part[1 * NROWS + j];
        float p2 = g_part[2 * NROWS + j];
        float p3 = g_part[3 * NROWS + j];
        float sq = g_sq[j];
        if (j < NHALF) {
            float m = fmaxf(fmaxf(p0, p1), fmaxf(p2, p3));
            s1 += sqrtf(fmaxf(m + sq, 0.f));
        } else {
            float m = fminf(fminf(p0, p1), fminf(p2, p3));
            float d = sqrtf(fmaxf(m + sq, 0.f));
            s2 += fmaxf(TMARGIN - d, 0.f);
        }
    }
    #pragma unroll
    for (int off = 32; off > 0; off >>= 1) {
        s1 += __shfl_xor(s1, off);
        s2 += __shfl_xor(s2, off);
    }
    __shared__ float r1[4], r2[4];
    int w = tid >> 6, lane = tid & 63;
    if (lane == 0) { r1[w] = s1; r2[w] = s2; }
    __syncthreads();
    if (tid == 0) {
        float a = r1[0] + r1[1] + r1[2] + r1[3];
        float b = r2[0] + r2[1] + r2[2] + r2[3];
        out[0] = a / (float)NHALF + b / (float)NHALF;
    }
}

extern "C" void kernel_launch(void* const* d_in, const int* in_sizes, int n_in,
                              void* d_out, int out_size, void* d_ws, size_t ws_size,
                              hipStream_t stream) {
    const float* feats = (const float*)d_in[0];
    float* out = (float*)d_out;
    hipLaunchKernelGGL(prep_kernel,   dim3(NROWS / 4), dim3(256), 0, stream, feats);
    hipLaunchKernelGGL(dist_kernel,   dim3(128, 2),    dim3(256), 0, stream);
    hipLaunchKernelGGL(finish_kernel, dim3(1),         dim3(256), 0, stream, out);
}

// Round 7
// 257.000 us; speedup vs baseline: 1.0527x; 1.0527x over previous
//
#include <hip/hip_runtime.h>
#include <hip/hip_bf16.h>

#define NROWS 16384      // total feats rows
#define NHALF 8192       // normal rows
#define KDIM  256
#define TMARGIN 100.0f
#define NSPLIT 8         // row-range splits, aligned to the 8 XCDs

typedef __bf16 bf16x8 __attribute__((ext_vector_type(8)));
typedef __bf16 bf16x4 __attribute__((ext_vector_type(4)));
typedef float  f32x4  __attribute__((ext_vector_type(4)));

// Static device scratch; fully rewritten every call.
__device__ __bf16 g_bf[NROWS * KDIM];           // bf16 copy of feats
__device__ float  g_sq[NROWS];                  // row squared norms (fp32)
__device__ float  g_part[2 * NSPLIT * NROWS];   // per-column partials of (sqa - 2c)

// ---------------- Kernel 1: convert fp32 -> bf16, compute row norms ----------------
__global__ __launch_bounds__(256) void prep_kernel(const float* __restrict__ feats) {
    int w    = threadIdx.x >> 6;
    int lane = threadIdx.x & 63;
    int row  = blockIdx.x * 4 + w;

    const float* rp = feats + (size_t)row * KDIM + lane * 4;
    float4 v = *(const float4*)rp;

    bf16x4 b;
    b[0] = (__bf16)v.x; b[1] = (__bf16)v.y; b[2] = (__bf16)v.z; b[3] = (__bf16)v.w;
    *(bf16x4*)(g_bf + (size_t)row * KDIM + lane * 4) = b;

    float sq = v.x*v.x + v.y*v.y + v.z*v.z + v.w*v.w;
    #pragma unroll
    for (int off = 32; off > 0; off >>= 1) sq += __shfl_xor(sq, off);
    if (lane == 0) g_sq[row] = sq;
}

// ---------------- Kernel 2: fused distance GEMM + column max/min fold ----------------
// Grid: 1024 blocks = 128 col-blocks x 8 row-splits; msplit = bid&7 -> XCD-aligned
// (all blocks sharing a 1024-row A-slice land on one XCD; 512 KB slice is L2-resident).
// Block: 4 waves (2 wr x 2 wc). Wave tile 64x64 = 4x4 MFMA 16x16x32, K=256 (8 k-steps).
// B panel (128 cols x K) register-resident. A fragments double-buffered (aA/aB) with
// one-k-step-ahead prefetch, crossing iteration boundaries.
__global__ __launch_bounds__(256, 2) void dist_kernel() {
    int tid  = threadIdx.x;
    int w    = tid >> 6;
    int lane = tid & 63;
    int wr   = w >> 1;
    int wc   = w & 1;
    int l15  = lane & 15;
    int lh   = lane >> 4;

    int bid      = blockIdx.x;
    int ms       = bid & 7;            // XCD-aligned row-split
    int colblock = bid >> 3;           // 0..127
    int colbase  = colblock * 128 + wc * 64;
    bool minmode = colblock >= 64;     // cols >= 8192 -> abnormal half (min)

    // ---- B panel: 4 col-16-tiles x 8 k-steps, register-resident ----
    bf16x8 Bfrag[4][8];
    #pragma unroll
    for (int n = 0; n < 4; ++n) {
        int col = colbase + n * 16 + l15;
        const __bf16* bp = g_bf + (size_t)col * KDIM + lh * 8;
        #pragma unroll
        for (int s = 0; s < 8; ++s)
            Bfrag[n][s] = *(const bf16x8*)(bp + s * 32);
    }

    float init = minmode ? 3.0e38f : -3.0e38f;
    float m_run[4] = {init, init, init, init};

    int row_lo = ms * 1024 + wr * 64;

#define LOADA(BUF, RB, S)                                                          \
    {                                                                              \
        _Pragma("unroll")                                                          \
        for (int m = 0; m < 4; ++m)                                                \
            BUF[m] = *(const bf16x8*)(g_bf + (size_t)((RB) + m * 16 + l15) * KDIM  \
                                      + (S) * 32 + lh * 8);                        \
    }

#define MFMASTEP(BUF, S)                                                           \
    {                                                                              \
        _Pragma("unroll")                                                          \
        for (int m = 0; m < 4; ++m)                                                \
            _Pragma("unroll")                                                      \
            for (int n = 0; n < 4; ++n)                                            \
                acc[m][n] = __builtin_amdgcn_mfma_f32_16x16x32_bf16(               \
                    BUF[m], Bfrag[n][S], acc[m][n], 0, 0, 0);                      \
    }

    bf16x8 aA[4], aB[4];
    LOADA(aA, row_lo, 0);

    for (int it = 0; it < 8; ++it) {
        int rbase = row_lo + it * 128;
        int rnext = row_lo + (it == 7 ? 7 : it + 1) * 128;  // clamped (redundant tail load)

        f32x4 acc[4][4];
        #pragma unroll
        for (int m = 0; m < 4; ++m)
            #pragma unroll
            for (int n = 0; n < 4; ++n)
                acc[m][n] = (f32x4){0.f, 0.f, 0.f, 0.f};

        LOADA(aB, rbase, 1); MFMASTEP(aA, 0);
        LOADA(aA, rbase, 2); MFMASTEP(aB, 1);
        LOADA(aB, rbase, 3); MFMASTEP(aA, 2);
        LOADA(aA, rbase, 4); MFMASTEP(aB, 3);
        LOADA(aB, rbase, 5); MFMASTEP(aA, 4);
        LOADA(aA, rbase, 6); MFMASTEP(aB, 5);
        LOADA(aB, rbase, 7); MFMASTEP(aA, 6);
        LOADA(aA, rnext, 0); MFMASTEP(aB, 7);

        // epilogue: fold t = sqa[row] - 2*c into per-column running max/min
        #pragma unroll
        for (int m = 0; m < 4; ++m) {
            f32x4 sq = *(const f32x4*)(g_sq + rbase + m * 16 + lh * 4);
            #pragma unroll
            for (int n = 0; n < 4; ++n) {
                #pragma unroll
                for (int r = 0; r < 4; ++r) {
                    float t = sq[r] - 2.0f * acc[m][n][r];
                    m_run[n] = minmode ? fminf(m_run[n], t) : fmaxf(m_run[n], t);
                }
            }
        }
    }
#undef LOADA
#undef MFMASTEP

    // lanes {l, l^16, l^32, l^48} hold the same column
    #pragma unroll
    for (int n = 0; n < 4; ++n) {
        float v = m_run[n];
        float v1 = __shfl_xor(v, 16);
        v = minmode ? fminf(v, v1) : fmaxf(v, v1);
        v1 = __shfl_xor(v, 32);
        v = minmode ? fminf(v, v1) : fmaxf(v, v1);
        m_run[n] = v;
    }
    if (lane < 16) {
        int pslot = ms * 2 + wr;           // 0..15
        #pragma unroll
        for (int n = 0; n < 4; ++n)
            g_part[pslot * NROWS + colbase + n * 16 + lane] = m_run[n];
    }
}

// ---------------- Kernel 3: combine partials, sqrt, means, scalar out ----------------
__global__ __launch_bounds__(256) void finish_kernel(float* __restrict__ out) {
    int tid = threadIdx.x;
    float s1 = 0.f, s2 = 0.f;
    for (int j = tid; j < NROWS; j += 256) {
        float sq = g_sq[j];
        if (j < NHALF) {
            float m = -3.0e38f;
            #pragma unroll
            for (int t = 0; t < 2 * NSPLIT; ++t)
                m = fmaxf(m, g_part[t * NROWS + j]);
            s1 += sqrtf(fmaxf(m + sq, 0.f));
        } else {
            float m = 3.0e38f;
            #pragma unroll
            for (int t = 0; t < 2 * NSPLIT; ++t)
                m = fminf(m, g_part[t * NROWS + j]);
            float d = sqrtf(fmaxf(m + sq, 0.f));
            s2 += fmaxf(TMARGIN - d, 0.f);
        }
    }
    #pragma unroll
    for (int off = 32; off > 0; off >>= 1) {
        s1 += __shfl_xor(s1, off);
        s2 += __shfl_xor(s2, off);
    }
    __shared__ float r1[4], r2[4];
    int w = tid >> 6, lane = tid & 63;
    if (lane == 0) { r1[w] = s1; r2[w] = s2; }
    __syncthreads();
    if (tid == 0) {
        float a = r1[0] + r1[1] + r1[2] + r1[3];
        float b = r2[0] + r2[1] + r2[2] + r2[3];
        out[0] = a / (float)NHALF + b / (float)NHALF;
    }
}

extern "C" void kernel_launch(void* const* d_in, const int* in_sizes, int n_in,
                              void* d_out, int out_size, void* d_ws, size_t ws_size,
                              hipStream_t stream) {
    const float* feats = (const float*)d_in[0];
    float* out = (float*)d_out;
    hipLaunchKernelGGL(prep_kernel,   dim3(NROWS / 4),    dim3(256), 0, stream, feats);
    hipLaunchKernelGGL(dist_kernel,   dim3(128 * NSPLIT), dim3(256), 0, stream);
    hipLaunchKernelGGL(finish_kernel, dim3(1),            dim3(256), 0, stream, out);
}

// Round 9
// 222.272 us; speedup vs baseline: 1.2172x; 1.1562x over previous
//
#include <hip/hip_runtime.h>
#include <hip/hip_bf16.h>

#define NROWS 16384      // total feats rows
#define NHALF 8192       // normal rows
#define KDIM  256
#define TMARGIN 100.0f

#define BM 128                              // rows per block (LDS-staged)
#define NROWBLK (NHALF / BM)                // 64
#define NCOLSPLIT 16                        // col panels (pinned to XCD via bid&15)
#define COLS_PER_SPLIT (NROWS / NCOLSPLIT)  // 1024
#define CC_ITERS (COLS_PER_SPLIT / 128)     // 8 col-chunks of 128 per block

typedef __bf16 bf16x8 __attribute__((ext_vector_type(8)));
typedef __bf16 bf16x4 __attribute__((ext_vector_type(4)));
typedef float  f32x4  __attribute__((ext_vector_type(4)));

// Static device scratch; fully rewritten every call.
__device__ __bf16 g_bf[NROWS * KDIM];                 // bf16 copy of feats
__device__ float  g_sq[NROWS];                        // row squared norms
__device__ float  g_part[2 * NROWBLK * NROWS];        // per-col partials of (sqa - 2c), 8 MB
__device__ float  g_colres[NROWS];                    // per-col final (sqrt'd / hinged)

// ---------------- Kernel 1: fp32 -> bf16 + row norms ----------------
__global__ __launch_bounds__(256) void prep_kernel(const float* __restrict__ feats) {
    int w    = threadIdx.x >> 6;
    int lane = threadIdx.x & 63;
    int row  = blockIdx.x * 4 + w;

    const float* rp = feats + (size_t)row * KDIM + lane * 4;
    float4 v = *(const float4*)rp;

    bf16x4 b;
    b[0] = (__bf16)v.x; b[1] = (__bf16)v.y; b[2] = (__bf16)v.z; b[3] = (__bf16)v.w;
    *(bf16x4*)(g_bf + (size_t)row * KDIM + lane * 4) = b;

    float sq = v.x*v.x + v.y*v.y + v.z*v.z + v.w*v.w;
    #pragma unroll
    for (int off = 32; off > 0; off >>= 1) sq += __shfl_xor(sq, off);
    if (lane == 0) g_sq[row] = sq;
}

// ---------------- Kernel 2: A-in-LDS distance GEMM + column fold ----------------
// Block = 4 waves (2 wr x 2 wc). A tile (128 rows x K=256) staged once in LDS
// (XOR-swizzled, bits 4-6); main loop has NO barriers. B streamed from L2 with
// one-k-step register prefetch. Per col-chunk (128 cols): 8 k-steps x 16 MFMA,
// then fold t = sq_row - 2c into per-column partial max/min.
__global__ __launch_bounds__(256, 2) void dist_kernel() {
    __shared__ __align__(16) char smem[BM * KDIM * 2];   // 64 KB

    int tid  = threadIdx.x;
    int w    = tid >> 6;
    int lane = tid & 63;
    int wr   = w >> 1;
    int wc   = w & 1;
    int l15  = lane & 15;
    int lh   = lane >> 4;

    int bid      = blockIdx.x;
    int colsplit = bid & (NCOLSPLIT - 1);    // XCD-pinned B panel
    int rowblk   = bid >> 4;                 // 0..63
    bool minmode = colsplit >= (NCOLSPLIT / 2);

    // ---- stage A tile into LDS (swizzled: byte ^= (row&7)<<4 within row) ----
    {
        const __bf16* src = g_bf + (size_t)rowblk * BM * KDIM;
        #pragma unroll
        for (int i = 0; i < 16; ++i) {
            int chunk = tid + i * 256;          // 0..4095 16B-chunks
            int row = chunk >> 5;               // 0..127
            int kc  = chunk & 31;               // 16B-chunk within row
            bf16x8 v = *(const bf16x8*)(src + row * KDIM + kc * 8);
            int dst = row * 512 + ((kc * 16) ^ ((row & 7) << 4));
            *(bf16x8*)(smem + dst) = v;
        }
    }
    __syncthreads();

    // Per-m, per-k-parity LDS bases; k-step s reads base[m][s&1] + (s>>1)*128
    // (XOR field is bits 4-6; bit 6 = s&1 folded into the base, bits 7-8 additive).
    int abase[4][2];
    #pragma unroll
    for (int m = 0; m < 4; ++m) {
        int row = wr * 64 + m * 16 + l15;
        #pragma unroll
        for (int p = 0; p < 2; ++p)
            abase[m][p] = row * 512 + (((p * 64) + lh * 16) ^ ((row & 7) << 4));
    }

    float init = minmode ? 3.0e38f : -3.0e38f;
    int rowglob = rowblk * BM + wr * 64;

    for (int cc = 0; cc < CC_ITERS; ++cc) {
        int colbase = colsplit * COLS_PER_SPLIT + cc * 128 + wc * 64;

        f32x4 acc[4][4];
        #pragma unroll
        for (int m = 0; m < 4; ++m)
            #pragma unroll
            for (int n = 0; n < 4; ++n)
                acc[m][n] = (f32x4){0.f, 0.f, 0.f, 0.f};

        bf16x8 A_[2][4], B_[2][4];
        #pragma unroll
        for (int m = 0; m < 4; ++m)
            A_[0][m] = *(const bf16x8*)(smem + abase[m][0]);
        #pragma unroll
        for (int n = 0; n < 4; ++n)
            B_[0][n] = *(const bf16x8*)(g_bf + (size_t)(colbase + n * 16 + l15) * KDIM + lh * 8);

        #pragma unroll
        for (int s = 0; s < 8; ++s) {
            const int cur = s & 1, nxt = cur ^ 1;
            if (s < 7) {
                const int sp = s + 1;
                #pragma unroll
                for (int m = 0; m < 4; ++m)
                    A_[nxt][m] = *(const bf16x8*)(smem + abase[m][sp & 1] + (sp >> 1) * 128);
                #pragma unroll
                for (int n = 0; n < 4; ++n)
                    B_[nxt][n] = *(const bf16x8*)(g_bf + (size_t)(colbase + n * 16 + l15) * KDIM
                                                  + sp * 32 + lh * 8);
            }
            #pragma unroll
            for (int m = 0; m < 4; ++m)
                #pragma unroll
                for (int n = 0; n < 4; ++n)
                    acc[m][n] = __builtin_amdgcn_mfma_f32_16x16x32_bf16(
                        A_[cur][m], B_[cur][n], acc[m][n], 0, 0, 0);
        }

        // fold t = sq_row - 2c into per-column running max/min (cols fresh per cc)
        float m_run[4] = {init, init, init, init};
        #pragma unroll
        for (int m = 0; m < 4; ++m) {
            f32x4 sq = *(const f32x4*)(g_sq + rowglob + m * 16 + lh * 4);
            #pragma unroll
            for (int n = 0; n < 4; ++n) {
                #pragma unroll
                for (int r = 0; r < 4; ++r) {
                    float t = sq[r] - 2.0f * acc[m][n][r];
                    m_run[n] = minmode ? fminf(m_run[n], t) : fmaxf(m_run[n], t);
                }
            }
        }
        // lanes {l, l^16, l^32, l^48} hold the same column
        #pragma unroll
        for (int n = 0; n < 4; ++n) {
            float v = m_run[n];
            float v1 = __shfl_xor(v, 16);
            v = minmode ? fminf(v, v1) : fmaxf(v, v1);
            v1 = __shfl_xor(v, 32);
            v = minmode ? fminf(v, v1) : fmaxf(v, v1);
            m_run[n] = v;
        }
        if (lane < 16) {
            int pslot = rowblk * 2 + wr;
            #pragma unroll
            for (int n = 0; n < 4; ++n)
                g_part[(size_t)pslot * NROWS + colbase + n * 16 + lane] = m_run[n];
        }
    }
}

// ---------------- Kernel 3: per-column reduce over 128 partials ----------------
__global__ __launch_bounds__(256) void finish1_kernel() {
    int col = blockIdx.x * 256 + threadIdx.x;        // grid 64 -> 16384 cols
    bool mn = col >= NHALF;
    float m = mn ? 3.0e38f : -3.0e38f;
    for (int p = 0; p < 2 * NROWBLK; ++p) {
        float v = g_part[(size_t)p * NROWS + col];   // coalesced across threads
        m = mn ? fminf(m, v) : fmaxf(m, v);
    }
    float d = sqrtf(fmaxf(m + g_sq[col], 0.f));
    g_colres[col] = mn ? fmaxf(TMARGIN - d, 0.f) : d;
}

// ---------------- Kernel 4: sum columns, scalar out ----------------
__global__ __launch_bounds__(256) void finish2_kernel(float* __restrict__ out) {
    int tid = threadIdx.x;
    float s1 = 0.f, s2 = 0.f;
    for (int j = tid; j < NROWS; j += 256) {
        float v = g_colres[j];
        if (j < NHALF) s1 += v; else s2 += v;
    }
    #pragma unroll
    for (int off = 32; off > 0; off >>= 1) {
        s1 += __shfl_xor(s1, off);
        s2 += __shfl_xor(s2, off);
    }
    __shared__ float r1[4], r2[4];
    int w = tid >> 6, lane = tid & 63;
    if (lane == 0) { r1[w] = s1; r2[w] = s2; }
    __syncthreads();
    if (tid == 0) {
        float a = r1[0] + r1[1] + r1[2] + r1[3];
        float b = r2[0] + r2[1] + r2[2] + r2[3];
        out[0] = a / (float)NHALF + b / (float)NHALF;
    }
}

extern "C" void kernel_launch(void* const* d_in, const int* in_sizes, int n_in,
                              void* d_out, int out_size, void* d_ws, size_t ws_size,
                              hipStream_t stream) {
    const float* feats = (const float*)d_in[0];
    float* out = (float*)d_out;
    hipLaunchKernelGGL(prep_kernel,    dim3(NROWS / 4),           dim3(256), 0, stream, feats);
    hipLaunchKernelGGL(dist_kernel,    dim3(NROWBLK * NCOLSPLIT), dim3(256), 0, stream);
    hipLaunchKernelGGL(finish1_kernel, dim3(NROWS / 256),         dim3(256), 0, stream);
    hipLaunchKernelGGL(finish2_kernel, dim3(1),                   dim3(256), 0, stream, out);
}